// Round 1
// baseline (829.545 us; speedup 1.0000x reference)
//
#include <hip/hip_runtime.h>
#include <math.h>

#define N_NODES 100000
#define N_EDGES 1600000
#define C 64
#define BN_EPS 1e-5f

// Workspace layout (float offsets)
//   h      : [N_NODES*64]  transformed features (25.6 MB)
//   deg    : [N_NODES]     degree -> deg_inv_sqrt (in place)
//   sum    : [64]          per-channel sum
//   sumsq  : [64]          per-channel sum of squares
//   scale  : [64]          gamma * inv_std
//   shift  : [64]          beta - mean*scale
#define WS_H     0
#define WS_DEG   6400000
#define WS_SUM   6500096
#define WS_SQ    6500160
#define WS_SCALE 6500224
#define WS_SHIFT 6500288

// ---------------- init: deg = 1 (self-loop), zero BN accumulators ----------
__global__ void k_init(float* __restrict__ deg, float* __restrict__ stats) {
    int i = blockIdx.x * blockDim.x + threadIdx.x;
    if (i < N_NODES) deg[i] = 1.0f;
    if (i < 128) stats[i] = 0.0f;   // sum[64] + sumsq[64] contiguous
}

// ---------------- h = x @ W^T  (W is [out,in] row-major) -------------------
// One wave per node; lane = output channel. W staged transposed in LDS so the
// per-k read Wt[k*64 + c] is consecutive across lanes (2 lanes/bank = free).
__global__ void k_gemm(const float* __restrict__ x, const float* __restrict__ W,
                       float* __restrict__ h) {
    __shared__ float Wt[64 * 64];
    for (int i = threadIdx.x; i < 64 * 64; i += blockDim.x)
        Wt[i] = W[((i & 63) << 6) + (i >> 6)];   // Wt[k*64+c] = W[c*64+k]
    __syncthreads();

    const int c = threadIdx.x & 63;
    int wid = blockIdx.x * (blockDim.x >> 6) + (threadIdx.x >> 6);
    const int nw = gridDim.x * (blockDim.x >> 6);
    for (int n = wid; n < N_NODES; n += nw) {
        const float* xr = x + n * 64;
        float acc = 0.0f;
        #pragma unroll
        for (int k = 0; k < 64; k += 4) {
            float4 xv = *reinterpret_cast<const float4*>(xr + k);  // wave-broadcast
            acc += xv.x * Wt[(k + 0) * 64 + c];
            acc += xv.y * Wt[(k + 1) * 64 + c];
            acc += xv.z * Wt[(k + 2) * 64 + c];
            acc += xv.w * Wt[(k + 3) * 64 + c];
        }
        h[n * 64 + c] = acc;
    }
}

// ---------------- degree histogram on dst ----------------------------------
__global__ void k_hist(const int* __restrict__ ei, float* __restrict__ deg) {
    int i = blockIdx.x * blockDim.x + threadIdx.x;
    const int st = gridDim.x * blockDim.x;
    for (int e = i; e < N_EDGES; e += st)
        atomicAdd(&deg[ei[N_EDGES + e]], 1.0f);
}

// ---------------- deg -> rsqrt(deg) in place (deg >= 1 always) -------------
__global__ void k_dinv(float* __restrict__ deg) {
    int i = blockIdx.x * blockDim.x + threadIdx.x;
    if (i < N_NODES) deg[i] = rsqrtf(deg[i]);
}

// ---------------- out = h * dinv^2 (self-loop term), float4 ----------------
__global__ void k_selfloop(const float* __restrict__ h, const float* __restrict__ dinv,
                           float* __restrict__ out) {
    int i = blockIdx.x * blockDim.x + threadIdx.x;
    const int st = gridDim.x * blockDim.x;
    const int total4 = N_NODES * C / 4;
    for (; i < total4; i += st) {
        int n = i >> 4;
        float w = dinv[n]; w = w * w;
        float4 v = reinterpret_cast<const float4*>(h)[i];
        v.x *= w; v.y *= w; v.z *= w; v.w *= w;
        reinterpret_cast<float4*>(out)[i] = v;
    }
}

// ---------------- edge scatter: out[dst] += h[src] * dinv[src]*dinv[dst] ---
// One wave per edge; lane = channel. Coalesced 256B gather, 64 lane-atomics.
__global__ void k_edge(const int* __restrict__ ei, const float* __restrict__ h,
                       const float* __restrict__ dinv, float* __restrict__ out) {
    const int c = threadIdx.x & 63;
    int wid = blockIdx.x * (blockDim.x >> 6) + (threadIdx.x >> 6);
    const int nw = gridDim.x * (blockDim.x >> 6);
    for (int e = wid; e < N_EDGES; e += nw) {
        int src = ei[e];
        int dst = ei[N_EDGES + e];
        float nrm = dinv[src] * dinv[dst];
        atomicAdd(&out[dst * 64 + c], h[src * 64 + c] * nrm);
    }
}

// ---------------- per-channel sum / sumsq over nodes -----------------------
__global__ void k_stats(const float* __restrict__ agg, float* __restrict__ sum,
                        float* __restrict__ sq) {
    __shared__ float ls[256], lq[256];
    const int tid = threadIdx.x;
    float s = 0.0f, q = 0.0f;
    int i = blockIdx.x * blockDim.x + tid;
    const int st = gridDim.x * blockDim.x;   // multiple of 64 -> channel fixed
    for (; i < N_NODES * C; i += st) {
        float v = agg[i];
        s += v; q += v * v;
    }
    ls[tid] = s; lq[tid] = q;
    __syncthreads();
    if (tid < 64) {
        s = ls[tid] + ls[tid + 64] + ls[tid + 128] + ls[tid + 192];
        q = lq[tid] + lq[tid + 64] + lq[tid + 128] + lq[tid + 192];
        atomicAdd(&sum[tid], s);
        atomicAdd(&sq[tid], q);
    }
}

// ---------------- BN finalize: scale/shift per channel ---------------------
__global__ void k_finalize(const float* __restrict__ sum, const float* __restrict__ sq,
                           const float* __restrict__ gamma, const float* __restrict__ beta,
                           float* __restrict__ scale, float* __restrict__ shift) {
    int c = threadIdx.x;
    if (c < 64) {
        float mean = sum[c] * (1.0f / N_NODES);
        float var  = sq[c] * (1.0f / N_NODES) - mean * mean;
        float inv  = rsqrtf(var + BN_EPS);
        float sc   = gamma[c] * inv;
        scale[c] = sc;
        shift[c] = beta[c] - mean * sc;
    }
}

// ---------------- y = relu(out*scale + shift), float4 in place -------------
__global__ void k_bnrelu(float* __restrict__ out, const float* __restrict__ scale,
                         const float* __restrict__ shift) {
    int i = blockIdx.x * blockDim.x + threadIdx.x;
    const int st = gridDim.x * blockDim.x;
    const int total4 = N_NODES * C / 4;
    for (; i < total4; i += st) {
        int c0 = (i & 15) << 2;
        float4 v = reinterpret_cast<float4*>(out)[i];
        v.x = fmaxf(v.x * scale[c0 + 0] + shift[c0 + 0], 0.0f);
        v.y = fmaxf(v.y * scale[c0 + 1] + shift[c0 + 1], 0.0f);
        v.z = fmaxf(v.z * scale[c0 + 2] + shift[c0 + 2], 0.0f);
        v.w = fmaxf(v.w * scale[c0 + 3] + shift[c0 + 3], 0.0f);
        reinterpret_cast<float4*>(out)[i] = v;
    }
}

extern "C" void kernel_launch(void* const* d_in, const int* in_sizes, int n_in,
                              void* d_out, int out_size, void* d_ws, size_t ws_size,
                              hipStream_t stream) {
    const float* x     = (const float*)d_in[0];
    const int*   ei    = (const int*)d_in[1];   // [2, E]: row0 = src, row1 = dst
    const float* W     = (const float*)d_in[2];
    // d_in[3] = b: a per-channel constant added before BatchNorm -> cancels in
    // (out - mean), so it has no effect on the final output. Unused.
    const float* gamma = (const float*)d_in[4];
    const float* beta  = (const float*)d_in[5];
    float* out = (float*)d_out;
    float* ws  = (float*)d_ws;

    float* h     = ws + WS_H;
    float* deg   = ws + WS_DEG;   // becomes deg_inv_sqrt after k_dinv
    float* sum   = ws + WS_SUM;
    float* sq    = ws + WS_SQ;
    float* scale = ws + WS_SCALE;
    float* shift = ws + WS_SHIFT;

    k_init<<<(N_NODES + 255) / 256, 256, 0, stream>>>(deg, sum);
    k_gemm<<<4096, 256, 0, stream>>>(x, W, h);
    k_hist<<<2048, 256, 0, stream>>>(ei, deg);
    k_dinv<<<(N_NODES + 255) / 256, 256, 0, stream>>>(deg);
    k_selfloop<<<4096, 256, 0, stream>>>(h, deg, out);
    k_edge<<<16384, 256, 0, stream>>>(ei, h, deg, out);
    k_stats<<<2048, 256, 0, stream>>>(out, sum, sq);
    k_finalize<<<1, 64, 0, stream>>>(sum, sq, gamma, beta, scale, shift);
    k_bnrelu<<<4096, 256, 0, stream>>>(out, scale, shift);
}

// Round 2
// 727.570 us; speedup vs baseline: 1.1402x; 1.1402x over previous
//
#include <hip/hip_runtime.h>
#include <math.h>

#define N_NODES 100000
#define N_EDGES 1600000
#define C 64
#define BN_EPS 1e-5f

// ---- workspace layout (float/uint32 slots) --------------------------------
// h        [6,400,000 f]  transformed features (25.6 MB)
// dinv     [100,000 f]
// rowptr   [100,001 u]    CSR row starts (exclusive scan of cnt)
// cnt      [100,000 u]    in-degree (excl. self-loop)
// cursor   [100,000 u]    scatter cursors
// blocksum [128 u]        scan partials
// csr_src  [1,600,000 u]  edge sources grouped by dst
// sum/sq/scale/shift [64 f each]
#define WS_H      0
#define WS_DINV   6400000
#define WS_ROWPTR 6500000
#define WS_CNT    6600064
#define WS_CURSOR 6700064
#define WS_BSUM   6800064
#define WS_CSR    6800192
#define WS_SUM    8400192
#define WS_SQ     8400256
#define WS_SCALE  8400320
#define WS_SHIFT  8400384

#define SCAN_ELEMS 1024               // 256 threads x 4 elems
#define SCAN_NBLK  ((N_NODES + SCAN_ELEMS - 1) / SCAN_ELEMS)   // 98

// ---------------- init: zero degree counts + BN accumulators ---------------
__global__ void k_init(unsigned* __restrict__ cnt, float* __restrict__ stats) {
    int i = blockIdx.x * blockDim.x + threadIdx.x;
    if (i < N_NODES) cnt[i] = 0u;
    if (i < 128) stats[i] = 0.0f;     // sum[64] + sumsq[64] contiguous
}

// ---------------- h = x @ W^T  (W is [out,in] row-major) -------------------
__global__ void k_gemm(const float* __restrict__ x, const float* __restrict__ W,
                       float* __restrict__ h) {
    __shared__ float Wt[64 * 64];
    for (int i = threadIdx.x; i < 64 * 64; i += blockDim.x)
        Wt[i] = W[((i & 63) << 6) + (i >> 6)];   // Wt[k*64+c] = W[c*64+k]
    __syncthreads();

    const int c = threadIdx.x & 63;
    int wid = blockIdx.x * (blockDim.x >> 6) + (threadIdx.x >> 6);
    const int nw = gridDim.x * (blockDim.x >> 6);
    for (int n = wid; n < N_NODES; n += nw) {
        const float* xr = x + n * 64;
        float acc = 0.0f;
        #pragma unroll
        for (int k = 0; k < 64; k += 4) {
            float4 xv = *reinterpret_cast<const float4*>(xr + k);  // wave-broadcast
            acc += xv.x * Wt[(k + 0) * 64 + c];
            acc += xv.y * Wt[(k + 1) * 64 + c];
            acc += xv.z * Wt[(k + 2) * 64 + c];
            acc += xv.w * Wt[(k + 3) * 64 + c];
        }
        h[n * 64 + c] = acc;
    }
}

// ---------------- in-degree histogram on dst (int atomics, 400 KB table) ---
__global__ void k_hist(const int* __restrict__ ei, unsigned* __restrict__ cnt) {
    int i = blockIdx.x * blockDim.x + threadIdx.x;
    const int st = gridDim.x * blockDim.x;
    for (int e = i; e < N_EDGES; e += st)
        atomicAdd(&cnt[ei[N_EDGES + e]], 1u);
}

// ---------------- scan step 1: per-block exclusive scan of cnt -------------
__global__ void k_scan1(const unsigned* __restrict__ cnt, unsigned* __restrict__ rowptr,
                        unsigned* __restrict__ bsum) {
    __shared__ unsigned ls[256];
    const int tid = threadIdx.x;
    const int base = blockIdx.x * SCAN_ELEMS + tid * 4;
    unsigned v[4];
    #pragma unroll
    for (int k = 0; k < 4; ++k) {
        int i = base + k;
        v[k] = (i < N_NODES) ? cnt[i] : 0u;
    }
    unsigned tsum = v[0] + v[1] + v[2] + v[3];
    ls[tid] = tsum;
    __syncthreads();
    // Hillis-Steele inclusive scan over 256 thread sums
    #pragma unroll
    for (int off = 1; off < 256; off <<= 1) {
        unsigned add = (tid >= off) ? ls[tid - off] : 0u;
        __syncthreads();
        ls[tid] += add;
        __syncthreads();
    }
    unsigned texcl = ls[tid] - tsum;               // exclusive base for this thread
    unsigned run = texcl;
    #pragma unroll
    for (int k = 0; k < 4; ++k) {
        int i = base + k;
        if (i < N_NODES) rowptr[i] = run;
        run += v[k];
    }
    if (tid == 255) bsum[blockIdx.x] = ls[255];    // block total
}

// ---------------- scan step 2: exclusive scan of 98 block sums -------------
__global__ void k_scan2(unsigned* __restrict__ bsum) {
    if (threadIdx.x == 0) {
        unsigned run = 0;
        for (int b = 0; b < SCAN_NBLK; ++b) {
            unsigned t = bsum[b];
            bsum[b] = run;
            run += t;
        }
    }
}

// ---------------- scan step 3: add block offsets; cursor copy; dinv --------
__global__ void k_scan3(unsigned* __restrict__ rowptr, const unsigned* __restrict__ bsum,
                        unsigned* __restrict__ cursor, const unsigned* __restrict__ cnt,
                        float* __restrict__ dinv) {
    int i = blockIdx.x * blockDim.x + threadIdx.x;
    if (i < N_NODES) {
        unsigned r = rowptr[i] + bsum[i / SCAN_ELEMS];
        rowptr[i] = r;
        cursor[i] = r;
        dinv[i] = rsqrtf((float)(cnt[i] + 1u));    // +1 self-loop
    }
}

// ---------------- scatter edges into CSR buckets ---------------------------
__global__ void k_scatter(const int* __restrict__ ei, unsigned* __restrict__ cursor,
                          unsigned* __restrict__ csr) {
    int i = blockIdx.x * blockDim.x + threadIdx.x;
    const int st = gridDim.x * blockDim.x;
    for (int e = i; e < N_EDGES; e += st) {
        int dst = ei[N_EDGES + e];
        unsigned pos = atomicAdd(&cursor[dst], 1u);
        csr[pos] = (unsigned)ei[e];
    }
}

// ---------------- gather-aggregate (atomic-free) + fused BN stats ----------
// One wave per node; lane = channel. acc starts with the self-loop term.
__global__ void k_agg(const unsigned* __restrict__ csr, const unsigned* __restrict__ rowptr,
                      const unsigned* __restrict__ cnt, const float* __restrict__ h,
                      const float* __restrict__ dinv, float* __restrict__ out,
                      float* __restrict__ sum, float* __restrict__ sq) {
    __shared__ float ls[256], lq[256];
    const int tid = threadIdx.x;
    const int c = tid & 63;
    int wid = blockIdx.x * (blockDim.x >> 6) + (tid >> 6);
    const int nw = gridDim.x * (blockDim.x >> 6);
    float s = 0.0f, q = 0.0f;
    for (int n = wid; n < N_NODES; n += nw) {
        float dn = dinv[n];
        float acc = h[n * 64 + c] * dn * dn;       // self-loop
        unsigned beg = rowptr[n];
        unsigned num = cnt[n];
        for (unsigned j = 0; j < num; ++j) {
            unsigned src = csr[beg + j];
            float w = dinv[src] * dn;
            acc += h[src * 64 + c] * w;
        }
        out[n * 64 + c] = acc;
        s += acc; q += acc * acc;
    }
    ls[tid] = s; lq[tid] = q;
    __syncthreads();
    if (tid < 64) {
        s = ls[tid] + ls[tid + 64] + ls[tid + 128] + ls[tid + 192];
        q = lq[tid] + lq[tid + 64] + lq[tid + 128] + lq[tid + 192];
        atomicAdd(&sum[tid], s);
        atomicAdd(&sq[tid], q);
    }
}

// ---------------- BN finalize: scale/shift per channel ---------------------
__global__ void k_finalize(const float* __restrict__ sum, const float* __restrict__ sq,
                           const float* __restrict__ gamma, const float* __restrict__ beta,
                           float* __restrict__ scale, float* __restrict__ shift) {
    int c = threadIdx.x;
    if (c < 64) {
        float mean = sum[c] * (1.0f / N_NODES);
        float var  = sq[c] * (1.0f / N_NODES) - mean * mean;
        float inv  = rsqrtf(var + BN_EPS);
        float sc   = gamma[c] * inv;
        scale[c] = sc;
        shift[c] = beta[c] - mean * sc;
    }
}

// ---------------- y = relu(out*scale + shift), float4 in place -------------
__global__ void k_bnrelu(float* __restrict__ out, const float* __restrict__ scale,
                         const float* __restrict__ shift) {
    int i = blockIdx.x * blockDim.x + threadIdx.x;
    const int st = gridDim.x * blockDim.x;
    const int total4 = N_NODES * C / 4;
    for (; i < total4; i += st) {
        int c0 = (i & 15) << 2;
        float4 v = reinterpret_cast<float4*>(out)[i];
        v.x = fmaxf(v.x * scale[c0 + 0] + shift[c0 + 0], 0.0f);
        v.y = fmaxf(v.y * scale[c0 + 1] + shift[c0 + 1], 0.0f);
        v.z = fmaxf(v.z * scale[c0 + 2] + shift[c0 + 2], 0.0f);
        v.w = fmaxf(v.w * scale[c0 + 3] + shift[c0 + 3], 0.0f);
        reinterpret_cast<float4*>(out)[i] = v;
    }
}

extern "C" void kernel_launch(void* const* d_in, const int* in_sizes, int n_in,
                              void* d_out, int out_size, void* d_ws, size_t ws_size,
                              hipStream_t stream) {
    const float* x     = (const float*)d_in[0];
    const int*   ei    = (const int*)d_in[1];   // [2, E]: row0 = src, row1 = dst
    const float* W     = (const float*)d_in[2];
    // d_in[3] = b: per-channel constant added before BatchNorm -> cancels in
    // (out - mean); unused.
    const float* gamma = (const float*)d_in[4];
    const float* beta  = (const float*)d_in[5];
    float* out = (float*)d_out;
    float*    wsf = (float*)d_ws;
    unsigned* wsu = (unsigned*)d_ws;

    float*    h      = wsf + WS_H;
    float*    dinv   = wsf + WS_DINV;
    unsigned* rowptr = wsu + WS_ROWPTR;
    unsigned* cnt    = wsu + WS_CNT;
    unsigned* cursor = wsu + WS_CURSOR;
    unsigned* bsum   = wsu + WS_BSUM;
    unsigned* csr    = wsu + WS_CSR;
    float*    sum    = wsf + WS_SUM;
    float*    sq     = wsf + WS_SQ;
    float*    scale  = wsf + WS_SCALE;
    float*    shift  = wsf + WS_SHIFT;

    k_init   <<<(N_NODES + 255) / 256, 256, 0, stream>>>(cnt, sum);
    k_gemm   <<<4096, 256, 0, stream>>>(x, W, h);
    k_hist   <<<2048, 256, 0, stream>>>(ei, cnt);
    k_scan1  <<<SCAN_NBLK, 256, 0, stream>>>(cnt, rowptr, bsum);
    k_scan2  <<<1, 64, 0, stream>>>(bsum);
    k_scan3  <<<(N_NODES + 255) / 256, 256, 0, stream>>>(rowptr, bsum, cursor, cnt, dinv);
    k_scatter<<<2048, 256, 0, stream>>>(ei, cursor, csr);
    k_agg    <<<2048, 256, 0, stream>>>(csr, rowptr, cnt, h, dinv, out, sum, sq);
    k_finalize<<<1, 64, 0, stream>>>(sum, sq, gamma, beta, scale, shift);
    k_bnrelu <<<4096, 256, 0, stream>>>(out, scale, shift);
}

// Round 5
// 374.287 us; speedup vs baseline: 2.2163x; 1.9439x over previous
//
#include <hip/hip_runtime.h>
#include <math.h>

#define N_NODES 100000
#define N_EDGES 1600000
#define C 64
#define BN_EPS 1e-5f

// ---- workspace layout (float/uint32 slots) --------------------------------
// hp       [6,400,000 f]  h' = (x @ W^T) * dinv[n]  (25.6 MB)
// dinv     [100,000 f]
// rowptr   [100,000 u]
// cnt      [100,000 u]
// cursor   [100,000 u]
// bsum     [128 u]
// csr      [1,600,000 u]
// sum/sq   [64 f each]
#define WS_HP     0
#define WS_DINV   6400000
#define WS_ROWPTR 6500000
#define WS_CNT    6600064
#define WS_CURSOR 6700064
#define WS_BSUM   6800064
#define WS_CSR    6800192
#define WS_SUM    8400192
#define WS_SQ     8400256

#define SCAN_ELEMS 1024
#define SCAN_NBLK  ((N_NODES + SCAN_ELEMS - 1) / SCAN_ELEMS)   // 98

// ---------------- init: zero degree counts + BN accumulators ---------------
__global__ void r4_init(unsigned* __restrict__ cnt, float* __restrict__ stats) {
    int i = blockIdx.x * blockDim.x + threadIdx.x;
    if (i < N_NODES) cnt[i] = 0u;
    if (i < 128) stats[i] = 0.0f;     // sum[64] + sumsq[64] contiguous
}

// ---------------- in-degree histogram on dst (int4 loads) ------------------
__global__ void r4_hist(const int* __restrict__ ei, unsigned* __restrict__ cnt) {
    int i = blockIdx.x * blockDim.x + threadIdx.x;
    const int st = gridDim.x * blockDim.x;
    const int4* d4 = reinterpret_cast<const int4*>(ei + N_EDGES);
    for (int e = i; e < N_EDGES / 4; e += st) {
        int4 v = d4[e];
        atomicAdd(&cnt[v.x], 1u); atomicAdd(&cnt[v.y], 1u);
        atomicAdd(&cnt[v.z], 1u); atomicAdd(&cnt[v.w], 1u);
    }
}

// ---------------- scan step 1: per-block exclusive scan of cnt -------------
__global__ void r4_scan1(const unsigned* __restrict__ cnt, unsigned* __restrict__ rowptr,
                         unsigned* __restrict__ bsum) {
    __shared__ unsigned ls[256];
    const int tid = threadIdx.x;
    const int base = blockIdx.x * SCAN_ELEMS + tid * 4;
    unsigned v[4];
    #pragma unroll
    for (int k = 0; k < 4; ++k) {
        int i = base + k;
        v[k] = (i < N_NODES) ? cnt[i] : 0u;
    }
    unsigned tsum = v[0] + v[1] + v[2] + v[3];
    ls[tid] = tsum;
    __syncthreads();
    #pragma unroll
    for (int off = 1; off < 256; off <<= 1) {
        unsigned add = (tid >= off) ? ls[tid - off] : 0u;
        __syncthreads();
        ls[tid] += add;
        __syncthreads();
    }
    unsigned run = ls[tid] - tsum;
    #pragma unroll
    for (int k = 0; k < 4; ++k) {
        int i = base + k;
        if (i < N_NODES) rowptr[i] = run;
        run += v[k];
    }
    if (tid == 255) bsum[blockIdx.x] = ls[255];
}

// ---------------- scan step 2: exclusive scan of block sums ----------------
__global__ void r4_scan2(unsigned* __restrict__ bsum) {
    if (threadIdx.x == 0) {
        unsigned run = 0;
        for (int b = 0; b < SCAN_NBLK; ++b) {
            unsigned t = bsum[b];
            bsum[b] = run;
            run += t;
        }
    }
}

// ---------------- scan step 3: fixup rowptr; init cursor; dinv -------------
__global__ void r4_scan3(unsigned* __restrict__ rowptr, const unsigned* __restrict__ bsum,
                         unsigned* __restrict__ cursor, const unsigned* __restrict__ cnt,
                         float* __restrict__ dinv) {
    int i = blockIdx.x * blockDim.x + threadIdx.x;
    if (i < N_NODES) {
        unsigned r = rowptr[i] + bsum[i / SCAN_ELEMS];
        rowptr[i] = r;
        cursor[i] = r;
        dinv[i] = rsqrtf((float)(cnt[i] + 1u));    // +1 self-loop
    }
}

// ---------------- hp = (x @ W^T) * dinv[n] ---------------------------------
// Block = 256 thr. Wt[64][64] transposed in LDS; X[16][64] staged coalesced.
// Thread: c = tid&63, computes 4 nodes (wave w owns rows w*4..w*4+3).
// N_NODES = 16*6250 exactly -> no tail guards.
__global__ void r4_mm(const float* __restrict__ x, const float* __restrict__ W,
                      const float* __restrict__ dinv, float* __restrict__ hp) {
    __shared__ float Wt[64 * 64];
    __shared__ float X[16 * 64];
    const int tid = threadIdx.x;
    for (int i = tid; i < 64 * 64; i += 256)
        Wt[i] = W[((i & 63) << 6) + (i >> 6)];   // Wt[k*64+c] = W[c*64+k]

    const int c = tid & 63;
    const int w = tid >> 6;            // wave 0..3
    const int nrow = tid >> 4;         // 0..15 (X stage row)
    const int k4 = (tid & 15) << 2;    // X stage col
    const int ngroups = N_NODES / 16;  // 6250

    for (int g = blockIdx.x; g < ngroups; g += gridDim.x) {
        const int base = g * 16;
        __syncthreads();
        *reinterpret_cast<float4*>(X + nrow * 64 + k4) =
            *reinterpret_cast<const float4*>(x + (base + nrow) * 64 + k4);
        __syncthreads();

        float acc0 = 0.f, acc1 = 0.f, acc2 = 0.f, acc3 = 0.f;
        #pragma unroll
        for (int k = 0; k < 64; k += 4) {
            float w0 = Wt[(k + 0) * 64 + c];
            float w1 = Wt[(k + 1) * 64 + c];
            float w2 = Wt[(k + 2) * 64 + c];
            float w3 = Wt[(k + 3) * 64 + c];
            float4 x0 = *reinterpret_cast<const float4*>(X + (w * 4 + 0) * 64 + k);
            float4 x1 = *reinterpret_cast<const float4*>(X + (w * 4 + 1) * 64 + k);
            float4 x2 = *reinterpret_cast<const float4*>(X + (w * 4 + 2) * 64 + k);
            float4 x3 = *reinterpret_cast<const float4*>(X + (w * 4 + 3) * 64 + k);
            acc0 += x0.x * w0 + x0.y * w1 + x0.z * w2 + x0.w * w3;
            acc1 += x1.x * w0 + x1.y * w1 + x1.z * w2 + x1.w * w3;
            acc2 += x2.x * w0 + x2.y * w1 + x2.z * w2 + x2.w * w3;
            acc3 += x3.x * w0 + x3.y * w1 + x3.z * w2 + x3.w * w3;
        }
        const int n0 = base + w * 4;
        hp[(n0 + 0) * 64 + c] = acc0 * dinv[n0 + 0];
        hp[(n0 + 1) * 64 + c] = acc1 * dinv[n0 + 1];
        hp[(n0 + 2) * 64 + c] = acc2 * dinv[n0 + 2];
        hp[(n0 + 3) * 64 + c] = acc3 * dinv[n0 + 3];
    }
}

// ---------------- scatter edges into CSR buckets (int4 loads) --------------
__global__ void r4_scatter(const int* __restrict__ ei, unsigned* __restrict__ cursor,
                           unsigned* __restrict__ csr) {
    int i = blockIdx.x * blockDim.x + threadIdx.x;
    const int st = gridDim.x * blockDim.x;
    const int4* s4 = reinterpret_cast<const int4*>(ei);
    const int4* d4 = reinterpret_cast<const int4*>(ei + N_EDGES);
    for (int e = i; e < N_EDGES / 4; e += st) {
        int4 d = d4[e];
        int4 s = s4[e];
        csr[atomicAdd(&cursor[d.x], 1u)] = (unsigned)s.x;
        csr[atomicAdd(&cursor[d.y], 1u)] = (unsigned)s.y;
        csr[atomicAdd(&cursor[d.z], 1u)] = (unsigned)s.z;
        csr[atomicAdd(&cursor[d.w], 1u)] = (unsigned)s.w;
    }
}

// ---------------- gather-aggregate (atomic-free) + fused BN stats ----------
// out[n] = dinv[n] * ( hp[n] + sum_{src in N(n)} hp[src] )
__global__ void r4_agg(const unsigned* __restrict__ csr, const unsigned* __restrict__ rowptr,
                       const unsigned* __restrict__ cnt, const float* __restrict__ hp,
                       const float* __restrict__ dinv, float* __restrict__ out,
                       float* __restrict__ sum, float* __restrict__ sq) {
    __shared__ float ls[256], lq[256];
    const int tid = threadIdx.x;
    const int c = tid & 63;
    int wid = blockIdx.x * (blockDim.x >> 6) + (tid >> 6);
    const int nw = gridDim.x * (blockDim.x >> 6);
    float s = 0.0f, q = 0.0f;
    for (int n = wid; n < N_NODES; n += nw) {
        float acc = hp[n * 64 + c];                // self-loop term
        const unsigned beg = rowptr[n];
        const unsigned num = cnt[n];
        unsigned j = 0;
        for (; j + 4 <= num; j += 4) {
            unsigned s0 = csr[beg + j + 0];
            unsigned s1 = csr[beg + j + 1];
            unsigned s2 = csr[beg + j + 2];
            unsigned s3 = csr[beg + j + 3];
            float a0 = hp[s0 * 64 + c];
            float a1 = hp[s1 * 64 + c];
            float a2 = hp[s2 * 64 + c];
            float a3 = hp[s3 * 64 + c];
            acc += (a0 + a1) + (a2 + a3);
        }
        for (; j < num; ++j) acc += hp[csr[beg + j] * 64 + c];
        float o = acc * dinv[n];
        out[n * 64 + c] = o;
        s += o; q += o * o;
    }
    ls[tid] = s; lq[tid] = q;
    __syncthreads();
    if (tid < 64) {
        s = ls[tid] + ls[tid + 64] + ls[tid + 128] + ls[tid + 192];
        q = lq[tid] + lq[tid + 64] + lq[tid + 128] + lq[tid + 192];
        atomicAdd(&sum[tid], s);
        atomicAdd(&sq[tid], q);
    }
}

// ---------------- y = relu(out*scale + shift), finalize inlined ------------
// Grid-stride multiple of 16 float4s -> each thread's 4 channels invariant.
__global__ void r4_bnrelu(float* __restrict__ out, const float* __restrict__ sum,
                          const float* __restrict__ sq, const float* __restrict__ gamma,
                          const float* __restrict__ beta) {
    int i = blockIdx.x * blockDim.x + threadIdx.x;
    const int st = gridDim.x * blockDim.x;     // multiple of 16
    const int c0 = (i & 15) << 2;
    float scl[4], sft[4];
    #pragma unroll
    for (int k = 0; k < 4; ++k) {
        float mean = sum[c0 + k] * (1.0f / N_NODES);
        float var  = sq[c0 + k] * (1.0f / N_NODES) - mean * mean;
        float inv  = rsqrtf(var + BN_EPS);
        scl[k] = gamma[c0 + k] * inv;
        sft[k] = beta[c0 + k] - mean * scl[k];
    }
    const int total4 = N_NODES * C / 4;
    for (; i < total4; i += st) {
        float4 v = reinterpret_cast<float4*>(out)[i];
        v.x = fmaxf(v.x * scl[0] + sft[0], 0.0f);
        v.y = fmaxf(v.y * scl[1] + sft[1], 0.0f);
        v.z = fmaxf(v.z * scl[2] + sft[2], 0.0f);
        v.w = fmaxf(v.w * scl[3] + sft[3], 0.0f);
        reinterpret_cast<float4*>(out)[i] = v;
    }
}

extern "C" void kernel_launch(void* const* d_in, const int* in_sizes, int n_in,
                              void* d_out, int out_size, void* d_ws, size_t ws_size,
                              hipStream_t stream) {
    const float* x     = (const float*)d_in[0];
    const int*   ei    = (const int*)d_in[1];   // [2, E]: row0 = src, row1 = dst
    const float* W     = (const float*)d_in[2];
    // d_in[3] = b: cancels in BN (out - mean); unused.
    const float* gamma = (const float*)d_in[4];
    const float* beta  = (const float*)d_in[5];
    float* out = (float*)d_out;
    float*    wsf = (float*)d_ws;
    unsigned* wsu = (unsigned*)d_ws;

    float*    hp     = wsf + WS_HP;
    float*    dinv   = wsf + WS_DINV;
    unsigned* rowptr = wsu + WS_ROWPTR;
    unsigned* cnt    = wsu + WS_CNT;
    unsigned* cursor = wsu + WS_CURSOR;
    unsigned* bsum   = wsu + WS_BSUM;
    unsigned* csr    = wsu + WS_CSR;
    float*    sum    = wsf + WS_SUM;
    float*    sq     = wsf + WS_SQ;

    r4_init   <<<(N_NODES + 255) / 256, 256, 0, stream>>>(cnt, sum);
    r4_hist   <<<1024, 256, 0, stream>>>(ei, cnt);
    r4_scan1  <<<SCAN_NBLK, 256, 0, stream>>>(cnt, rowptr, bsum);
    r4_scan2  <<<1, 64, 0, stream>>>(bsum);
    r4_scan3  <<<(N_NODES + 255) / 256, 256, 0, stream>>>(rowptr, bsum, cursor, cnt, dinv);
    r4_mm     <<<2048, 256, 0, stream>>>(x, W, dinv, hp);
    r4_scatter<<<1024, 256, 0, stream>>>(ei, cursor, csr);
    r4_agg    <<<4096, 256, 0, stream>>>(csr, rowptr, cnt, hp, dinv, out, sum, sq);
    r4_bnrelu <<<1024, 256, 0, stream>>>(out, sum, sq, gamma, beta);
}

// Round 6
// 363.337 us; speedup vs baseline: 2.2831x; 1.0301x over previous
//
#include <hip/hip_runtime.h>
#include <math.h>

#define N_NODES 100000
#define N_EDGES 1600000
#define C 64
#define BN_EPS 1e-5f

// ---- workspace layout (float-slot offsets) --------------------------------
// hp_bf    ushort[6,400,000] = 3,200,000 f-slots : bf16 h' = (x@W^T)*dinv[n]
// dinv     f[100,000]
// rowptr   u[100,000]
// cnt      u[100,000]
// cursor   u[100,000]
// bsum     u[128]
// csr      u[1,600,000]
// sum/sq   f[64] each
#define WS_HP     0
#define WS_DINV   3200000
#define WS_ROWPTR 3300000
#define WS_CNT    3400000
#define WS_CURSOR 3500000
#define WS_BSUM   3600000
#define WS_CSR    3600128
#define WS_SUM    5200128
#define WS_SQ     5200192

#define SCAN_ELEMS 1024
#define SCAN_NBLK  ((N_NODES + SCAN_ELEMS - 1) / SCAN_ELEMS)   // 98

// bf16 helpers (RNE, no NaN handling needed for this data)
static __device__ __forceinline__ unsigned short f2bf(float f) {
    unsigned u = __float_as_uint(f);
    unsigned r = 0x7FFFu + ((u >> 16) & 1u);
    return (unsigned short)((u + r) >> 16);
}
static __device__ __forceinline__ float bf2f(unsigned short h) {
    return __uint_as_float(((unsigned)h) << 16);
}

// ---------------- init: zero degree counts + BN accumulators ---------------
__global__ void r5_init(unsigned* __restrict__ cnt, float* __restrict__ stats) {
    int i = blockIdx.x * blockDim.x + threadIdx.x;
    if (i < N_NODES) cnt[i] = 0u;
    if (i < 128) stats[i] = 0.0f;     // sum[64] + sumsq[64] contiguous
}

// ---------------- in-degree histogram on dst (int4 loads) ------------------
__global__ void r5_hist(const int* __restrict__ ei, unsigned* __restrict__ cnt) {
    int i = blockIdx.x * blockDim.x + threadIdx.x;
    const int st = gridDim.x * blockDim.x;
    const int4* d4 = reinterpret_cast<const int4*>(ei + N_EDGES);
    for (int e = i; e < N_EDGES / 4; e += st) {
        int4 v = d4[e];
        atomicAdd(&cnt[v.x], 1u); atomicAdd(&cnt[v.y], 1u);
        atomicAdd(&cnt[v.z], 1u); atomicAdd(&cnt[v.w], 1u);
    }
}

// ---------------- scan step 1: per-block exclusive scan of cnt -------------
__global__ void r5_scan1(const unsigned* __restrict__ cnt, unsigned* __restrict__ rowptr,
                         unsigned* __restrict__ bsum) {
    __shared__ unsigned ls[256];
    const int tid = threadIdx.x;
    const int base = blockIdx.x * SCAN_ELEMS + tid * 4;
    unsigned v[4];
    #pragma unroll
    for (int k = 0; k < 4; ++k) {
        int i = base + k;
        v[k] = (i < N_NODES) ? cnt[i] : 0u;
    }
    unsigned tsum = v[0] + v[1] + v[2] + v[3];
    ls[tid] = tsum;
    __syncthreads();
    #pragma unroll
    for (int off = 1; off < 256; off <<= 1) {
        unsigned add = (tid >= off) ? ls[tid - off] : 0u;
        __syncthreads();
        ls[tid] += add;
        __syncthreads();
    }
    unsigned run = ls[tid] - tsum;
    #pragma unroll
    for (int k = 0; k < 4; ++k) {
        int i = base + k;
        if (i < N_NODES) rowptr[i] = run;
        run += v[k];
    }
    if (tid == 255) bsum[blockIdx.x] = ls[255];
}

// ---------------- scan step 2: exclusive scan of block sums ----------------
__global__ void r5_scan2(unsigned* __restrict__ bsum) {
    if (threadIdx.x == 0) {
        unsigned run = 0;
        for (int b = 0; b < SCAN_NBLK; ++b) {
            unsigned t = bsum[b];
            bsum[b] = run;
            run += t;
        }
    }
}

// ---------------- scan step 3: fixup rowptr; init cursor; dinv -------------
__global__ void r5_scan3(unsigned* __restrict__ rowptr, const unsigned* __restrict__ bsum,
                         unsigned* __restrict__ cursor, const unsigned* __restrict__ cnt,
                         float* __restrict__ dinv) {
    int i = blockIdx.x * blockDim.x + threadIdx.x;
    if (i < N_NODES) {
        unsigned r = rowptr[i] + bsum[i / SCAN_ELEMS];
        rowptr[i] = r;
        cursor[i] = r;
        dinv[i] = rsqrtf((float)(cnt[i] + 1u));    // +1 self-loop
    }
}

// ---------------- hp_bf = bf16( (x @ W^T) * dinv[n] ) ----------------------
// Block = 256 thr. Wt[64][64] transposed in LDS; X[16][64] staged coalesced.
__global__ void r5_mm(const float* __restrict__ x, const float* __restrict__ W,
                      const float* __restrict__ dinv, unsigned short* __restrict__ hp) {
    __shared__ float Wt[64 * 64];
    __shared__ float X[16 * 64];
    const int tid = threadIdx.x;
    for (int i = tid; i < 64 * 64; i += 256)
        Wt[i] = W[((i & 63) << 6) + (i >> 6)];   // Wt[k*64+c] = W[c*64+k]

    const int c = tid & 63;
    const int w = tid >> 6;            // wave 0..3
    const int nrow = tid >> 4;         // 0..15 (X stage row)
    const int k4 = (tid & 15) << 2;    // X stage col
    const int ngroups = N_NODES / 16;  // 6250

    for (int g = blockIdx.x; g < ngroups; g += gridDim.x) {
        const int base = g * 16;
        __syncthreads();
        *reinterpret_cast<float4*>(X + nrow * 64 + k4) =
            *reinterpret_cast<const float4*>(x + (base + nrow) * 64 + k4);
        __syncthreads();

        float acc0 = 0.f, acc1 = 0.f, acc2 = 0.f, acc3 = 0.f;
        #pragma unroll
        for (int k = 0; k < 64; k += 4) {
            float w0 = Wt[(k + 0) * 64 + c];
            float w1 = Wt[(k + 1) * 64 + c];
            float w2 = Wt[(k + 2) * 64 + c];
            float w3 = Wt[(k + 3) * 64 + c];
            float4 x0 = *reinterpret_cast<const float4*>(X + (w * 4 + 0) * 64 + k);
            float4 x1 = *reinterpret_cast<const float4*>(X + (w * 4 + 1) * 64 + k);
            float4 x2 = *reinterpret_cast<const float4*>(X + (w * 4 + 2) * 64 + k);
            float4 x3 = *reinterpret_cast<const float4*>(X + (w * 4 + 3) * 64 + k);
            acc0 += x0.x * w0 + x0.y * w1 + x0.z * w2 + x0.w * w3;
            acc1 += x1.x * w0 + x1.y * w1 + x1.z * w2 + x1.w * w3;
            acc2 += x2.x * w0 + x2.y * w1 + x2.z * w2 + x2.w * w3;
            acc3 += x3.x * w0 + x3.y * w1 + x3.z * w2 + x3.w * w3;
        }
        const int n0 = base + w * 4;
        hp[(n0 + 0) * 64 + c] = f2bf(acc0 * dinv[n0 + 0]);
        hp[(n0 + 1) * 64 + c] = f2bf(acc1 * dinv[n0 + 1]);
        hp[(n0 + 2) * 64 + c] = f2bf(acc2 * dinv[n0 + 2]);
        hp[(n0 + 3) * 64 + c] = f2bf(acc3 * dinv[n0 + 3]);
    }
}

// ---------------- scatter edges into CSR buckets (int4 loads) --------------
__global__ void r5_scatter(const int* __restrict__ ei, unsigned* __restrict__ cursor,
                           unsigned* __restrict__ csr) {
    int i = blockIdx.x * blockDim.x + threadIdx.x;
    const int st = gridDim.x * blockDim.x;
    const int4* s4 = reinterpret_cast<const int4*>(ei);
    const int4* d4 = reinterpret_cast<const int4*>(ei + N_EDGES);
    for (int e = i; e < N_EDGES / 4; e += st) {
        int4 d = d4[e];
        int4 s = s4[e];
        csr[atomicAdd(&cursor[d.x], 1u)] = (unsigned)s.x;
        csr[atomicAdd(&cursor[d.y], 1u)] = (unsigned)s.y;
        csr[atomicAdd(&cursor[d.z], 1u)] = (unsigned)s.z;
        csr[atomicAdd(&cursor[d.w], 1u)] = (unsigned)s.w;
    }
}

// ---------------- gather-aggregate (bf16 gathers) + fused BN stats ---------
// out[n] = dinv[n] * ( hp[n] + sum_{src in N(n)} hp[src] )
__global__ void r5_agg(const unsigned* __restrict__ csr, const unsigned* __restrict__ rowptr,
                       const unsigned* __restrict__ cnt, const unsigned short* __restrict__ hp,
                       const float* __restrict__ dinv, float* __restrict__ out,
                       float* __restrict__ sum, float* __restrict__ sq) {
    __shared__ float ls[256], lq[256];
    const int tid = threadIdx.x;
    const int c = tid & 63;
    int wid = blockIdx.x * (blockDim.x >> 6) + (tid >> 6);
    const int nw = gridDim.x * (blockDim.x >> 6);
    float s = 0.0f, q = 0.0f;
    for (int n = wid; n < N_NODES; n += nw) {
        float acc = bf2f(hp[n * 64 + c]);          // self-loop term
        const unsigned beg = rowptr[n];
        const unsigned num = cnt[n];
        unsigned j = 0;
        for (; j + 8 <= num; j += 8) {
            unsigned s0 = csr[beg + j + 0];
            unsigned s1 = csr[beg + j + 1];
            unsigned s2 = csr[beg + j + 2];
            unsigned s3 = csr[beg + j + 3];
            unsigned s4 = csr[beg + j + 4];
            unsigned s5 = csr[beg + j + 5];
            unsigned s6 = csr[beg + j + 6];
            unsigned s7 = csr[beg + j + 7];
            float a0 = bf2f(hp[s0 * 64 + c]);
            float a1 = bf2f(hp[s1 * 64 + c]);
            float a2 = bf2f(hp[s2 * 64 + c]);
            float a3 = bf2f(hp[s3 * 64 + c]);
            float a4 = bf2f(hp[s4 * 64 + c]);
            float a5 = bf2f(hp[s5 * 64 + c]);
            float a6 = bf2f(hp[s6 * 64 + c]);
            float a7 = bf2f(hp[s7 * 64 + c]);
            acc += ((a0 + a1) + (a2 + a3)) + ((a4 + a5) + (a6 + a7));
        }
        for (; j + 4 <= num; j += 4) {
            unsigned s0 = csr[beg + j + 0];
            unsigned s1 = csr[beg + j + 1];
            unsigned s2 = csr[beg + j + 2];
            unsigned s3 = csr[beg + j + 3];
            float a0 = bf2f(hp[s0 * 64 + c]);
            float a1 = bf2f(hp[s1 * 64 + c]);
            float a2 = bf2f(hp[s2 * 64 + c]);
            float a3 = bf2f(hp[s3 * 64 + c]);
            acc += (a0 + a1) + (a2 + a3);
        }
        for (; j < num; ++j) acc += bf2f(hp[csr[beg + j] * 64 + c]);
        float o = acc * dinv[n];
        out[n * 64 + c] = o;
        s += o; q += o * o;
    }
    ls[tid] = s; lq[tid] = q;
    __syncthreads();
    if (tid < 64) {
        s = ls[tid] + ls[tid + 64] + ls[tid + 128] + ls[tid + 192];
        q = lq[tid] + lq[tid + 64] + lq[tid + 128] + lq[tid + 192];
        atomicAdd(&sum[tid], s);
        atomicAdd(&sq[tid], q);
    }
}

// ---------------- y = relu(out*scale + shift), finalize inlined ------------
__global__ void r5_bnrelu(float* __restrict__ out, const float* __restrict__ sum,
                          const float* __restrict__ sq, const float* __restrict__ gamma,
                          const float* __restrict__ beta) {
    int i = blockIdx.x * blockDim.x + threadIdx.x;
    const int st = gridDim.x * blockDim.x;     // multiple of 16
    const int c0 = (i & 15) << 2;
    float scl[4], sft[4];
    #pragma unroll
    for (int k = 0; k < 4; ++k) {
        float mean = sum[c0 + k] * (1.0f / N_NODES);
        float var  = sq[c0 + k] * (1.0f / N_NODES) - mean * mean;
        float inv  = rsqrtf(var + BN_EPS);
        scl[k] = gamma[c0 + k] * inv;
        sft[k] = beta[c0 + k] - mean * scl[k];
    }
    const int total4 = N_NODES * C / 4;
    for (; i < total4; i += st) {
        float4 v = reinterpret_cast<float4*>(out)[i];
        v.x = fmaxf(v.x * scl[0] + sft[0], 0.0f);
        v.y = fmaxf(v.y * scl[1] + sft[1], 0.0f);
        v.z = fmaxf(v.z * scl[2] + sft[2], 0.0f);
        v.w = fmaxf(v.w * scl[3] + sft[3], 0.0f);
        reinterpret_cast<float4*>(out)[i] = v;
    }
}

extern "C" void kernel_launch(void* const* d_in, const int* in_sizes, int n_in,
                              void* d_out, int out_size, void* d_ws, size_t ws_size,
                              hipStream_t stream) {
    const float* x     = (const float*)d_in[0];
    const int*   ei    = (const int*)d_in[1];   // [2, E]: row0 = src, row1 = dst
    const float* W     = (const float*)d_in[2];
    // d_in[3] = b: cancels in BN (out - mean); unused.
    const float* gamma = (const float*)d_in[4];
    const float* beta  = (const float*)d_in[5];
    float* out = (float*)d_out;
    float*    wsf = (float*)d_ws;
    unsigned* wsu = (unsigned*)d_ws;

    unsigned short* hp = (unsigned short*)((float*)d_ws + WS_HP);
    float*    dinv   = wsf + WS_DINV;
    unsigned* rowptr = wsu + WS_ROWPTR;
    unsigned* cnt    = wsu + WS_CNT;
    unsigned* cursor = wsu + WS_CURSOR;
    unsigned* bsum   = wsu + WS_BSUM;
    unsigned* csr    = wsu + WS_CSR;
    float*    sum    = wsf + WS_SUM;
    float*    sq     = wsf + WS_SQ;

    r5_init   <<<(N_NODES + 255) / 256, 256, 0, stream>>>(cnt, sum);
    r5_hist   <<<1024, 256, 0, stream>>>(ei, cnt);
    r5_scan1  <<<SCAN_NBLK, 256, 0, stream>>>(cnt, rowptr, bsum);
    r5_scan2  <<<1, 64, 0, stream>>>(bsum);
    r5_scan3  <<<(N_NODES + 255) / 256, 256, 0, stream>>>(rowptr, bsum, cursor, cnt, dinv);
    r5_mm     <<<2048, 256, 0, stream>>>(x, W, dinv, hp);
    r5_scatter<<<1024, 256, 0, stream>>>(ei, cursor, csr);
    r5_agg    <<<4096, 256, 0, stream>>>(csr, rowptr, cnt, hp, dinv, out, sum, sq);
    r5_bnrelu <<<1024, 256, 0, stream>>>(out, sum, sq, gamma, beta);
}